// Round 20
// baseline (119.376 us; speedup 1.0000x reference)
//
#include <hip/hip_runtime.h>
#include <cstdint>
#include <cstddef>

// Problem constants
#define BATCH 8
#define CDIM  512
#define NPIX  4096   // 64*64
#define NHEAD 8
#define DH    64
#define KTOK  64
#define MEM   512

typedef __attribute__((ext_vector_type(8))) short          bf8;   // MFMA A/B operand (8 bf16)
typedef __attribute__((ext_vector_type(4))) float          f4;    // MFMA C/D
typedef __attribute__((ext_vector_type(4))) unsigned short us4;   // 8-byte bf16 pack

__device__ __forceinline__ unsigned short f2bf(float f){
  union { float f; unsigned int u; } x; x.f = f;
  unsigned int r = (x.u + 0x7fffu + ((x.u >> 16) & 1u)) >> 16;
  return (unsigned short)r;
}

// async global->LDS DMA, 16B per lane; LDS dest = wave-uniform base + lane*16
__device__ __forceinline__ void gld_lds16(const unsigned short* g, unsigned short* lds){
  __builtin_amdgcn_global_load_lds((const __attribute__((address_space(1))) unsigned int*)g,
                                   (__attribute__((address_space(3))) unsigned int*)lds, 16, 0, 0);
}

// ---------------- K0: weights fp32 -> bf16 ----------------
__global__ __launch_bounds__(256) void wconv(const float* __restrict__ wq, const float* __restrict__ wp,
                                             unsigned short* __restrict__ wqb, unsigned short* __restrict__ wpb){
  int i = (blockIdx.x * 256 + threadIdx.x) * 4;   // grid 256 -> covers 262144
  float4 a = *(const float4*)(wq + i);
  us4 pa = { f2bf(a.x), f2bf(a.y), f2bf(a.z), f2bf(a.w) };
  *(us4*)(wqb + i) = pa;
  float4 b = *(const float4*)(wp + i);
  us4 pb = { f2bf(b.x), f2bf(b.y), f2bf(b.z), f2bf(b.w) };
  *(us4*)(wpb + i) = pb;
}

// ---------------- K0b: x [b][c][n] fp32 -> xb [b][n][c] bf16 ----------------
__global__ __launch_bounds__(256) void xtrans(const float* __restrict__ x, unsigned short* __restrict__ xb){
  __shared__ __align__(16) unsigned short t[64 * 68];
  int tid = threadIdx.x;
  int n0 = blockIdx.x * 64, c0 = blockIdx.y * 64, b = blockIdx.z;
  const float* xp = x + ((size_t)(b * CDIM + c0)) * NPIX + n0;
#pragma unroll
  for (int it = 0; it < 4; ++it){
    int idx = it * 1024 + tid * 4;
    int cc = idx >> 6, nn = idx & 63;
    float4 v = *(const float4*)(xp + (size_t)cc * NPIX + nn);
    us4 pk = { f2bf(v.x), f2bf(v.y), f2bf(v.z), f2bf(v.w) };
    *(us4*)&t[cc * 68 + nn] = pk;
  }
  __syncthreads();
  unsigned short* op = xb + ((size_t)(b * NPIX + n0)) * CDIM + c0;
#pragma unroll
  for (int it = 0; it < 4; ++it){
    int idx = it * 1024 + tid * 4;
    int nn = idx >> 6, c4 = idx & 63;
    us4 pk = { t[(c4 + 0) * 68 + nn], t[(c4 + 1) * 68 + nn],
               t[(c4 + 2) * 68 + nn], t[(c4 + 3) * 68 + nn] };
    *(us4*)(op + (size_t)nn * CDIM + c4) = pk;
  }
}

// ---------------- K1: K/V projection (fp32 compute, bf16 out) ----------------
__global__ __launch_bounds__(256) void kvproj(const float* __restrict__ Ft, const float* __restrict__ Wk,
                                              const float* __restrict__ Wv, unsigned short* __restrict__ kb,
                                              unsigned short* __restrict__ vt){
  __shared__ float ft[8][MEM];
  int tid = threadIdx.x;
  int cg = blockIdx.x, kk0 = blockIdx.y * 8, b = blockIdx.z;
  const float* fp = Ft + ((size_t)(b * KTOK + kk0)) * MEM;
#pragma unroll
  for (int it = 0; it < 4; ++it){
    int idx = it * 1024 + tid * 4;
    int row = idx >> 9, m = idx & 511;
    *(float4*)&ft[row][m] = *(const float4*)(fp + (size_t)row * MEM + m);
  }
  __syncthreads();
  int kv = tid >> 7, cl = tid & 127;
  int c = cg * 128 + cl;
  const float* wrow = (kv ? Wv : Wk) + (size_t)c * MEM;
  float acc[8] = {0.f,0.f,0.f,0.f,0.f,0.f,0.f,0.f};
  for (int m = 0; m < MEM; m += 4){
    float4 wv4 = *(const float4*)(wrow + m);
#pragma unroll
    for (int kk = 0; kk < 8; ++kk){
      acc[kk] += wv4.x * ft[kk][m] + wv4.y * ft[kk][m+1] + wv4.z * ft[kk][m+2] + wv4.w * ft[kk][m+3];
    }
  }
  int h = c >> 6, dd = c & 63;
  if (kv == 0){
#pragma unroll
    for (int kk = 0; kk < 8; ++kk)
      kb[(((size_t)(b * NHEAD + h)) * KTOK + kk0 + kk) * DH + dd] = f2bf(acc[kk] * 0.125f);
  } else {
#pragma unroll
    for (int kk = 0; kk < 8; ++kk)
      vt[(((size_t)(b * NHEAD + h)) * DH + dd) * KTOK + kk0 + kk] = f2bf(acc[kk]);
  }
}

// ====== GEMM geometry (R14-verified): 128o x 256n tile, 8 waves (2 o x 4 n), BK=64, ======
// ====== single-buffer {STAGE; sync; MFMA; sync}, conflict-free swizzle ======
// LDS: A [0,8192) rows 0..127 | B [8192,24576) rows 0..255 shorts; rows 128B, 16B chunks,
// phys chunk = logical ^ (row&7). STAGE: 48 DMAs/block = 6/wave (A groups {w,w+8},
// B groups {w,w+8,w+16,w+24}); lane l -> row l>>3 of its group, src pre-swizzled (l&7)^(l>>3).
#define GEMM_PRE(APTR, BPTR)                                                              \
  const int lrow = l >> 3;                                                                \
  const int lchk = (l & 7) ^ lrow;                                                        \
  const unsigned short* aS = (APTR) + (size_t)(o0 + w * 8 + lrow) * CDIM + lchk * 8;      \
  const unsigned short* bS = (BPTR) + ((size_t)(b * NPIX) + n0 + w * 8 + lrow) * CDIM + lchk * 8;

#define STAGE(LDS, kc)                                                                    \
  {                                                                                       \
    gld_lds16(aS + (kc),                        &(LDS)[w * 512]);                         \
    gld_lds16(aS + (size_t)64 * CDIM + (kc),    &(LDS)[(w + 8) * 512]);                   \
    _Pragma("unroll")                                                                     \
    for (int j = 0; j < 4; ++j)                                                           \
      gld_lds16(bS + (size_t)j * 64 * CDIM + (kc), &(LDS)[8192 + (w + j * 8) * 512]);     \
  }

#define GEMM_STEP(LDS, ACC)                                                               \
  _Pragma("unroll")                                                                       \
  for (int ks = 0; ks < 2; ++ks){                                                         \
    bf8 af[4], bfr[4];                                                                    \
    _Pragma("unroll")                                                                     \
    for (int fi = 0; fi < 4; ++fi){                                                       \
      int r = ol + fi * 16 + lo;                                                          \
      af[fi] = *(const bf8*)&(LDS)[r * 64 + (((ks * 4 + hi) ^ (r & 7)) << 3)];            \
    }                                                                                     \
    _Pragma("unroll")                                                                     \
    for (int fj = 0; fj < 4; ++fj){                                                       \
      int r = nl + fj * 16 + lo;                                                          \
      bfr[fj] = *(const bf8*)&(LDS)[8192 + r * 64 + (((ks * 4 + hi) ^ (r & 7)) << 3)];    \
    }                                                                                     \
    _Pragma("unroll")                                                                     \
    for (int fi = 0; fi < 4; ++fi)                                                        \
      _Pragma("unroll")                                                                   \
      for (int fj = 0; fj < 4; ++fj)                                                      \
        ACC[fi][fj] = __builtin_amdgcn_mfma_f32_16x16x32_bf16(af[fi], bfr[fj], ACC[fi][fj], 0, 0, 0); \
  }

// ---------------- K2: fused q-projection + attention (48KB LDS: qt half-tiles fit in staging) ----------------
// grid (16,4,8). Wave w: head blockIdx.y*2+(w>>2), n-quarter (w&3). Attention tail runs in
// TWO 32-n halves so the per-wave qt/P tile is 32x64 (4KB); 8 waves x 4KB = 32KB aliases the
// 48KB staging region -> LDS 48KB -> 3 blocks/CU (matches pproj's measured occupancy).
__global__ __launch_bounds__(512, 4) void qattn(const unsigned short* __restrict__ wqb,
                                                const unsigned short* __restrict__ xb,
                                                const unsigned short* __restrict__ kb,
                                                const unsigned short* __restrict__ vt,
                                                unsigned short* __restrict__ att){
  __shared__ __align__(16) unsigned short r0[24576];   // 48 KB (staging; qt 8x4KB aliases)
  int tid = threadIdx.x;
  int w = tid >> 6, l = tid & 63;
  int lo = l & 15, hi = l >> 4;
  int n0 = blockIdx.x * 256, o0 = blockIdx.y * 128, b = blockIdx.z;
  int ol = (w >> 2) * 64, nl = (w & 3) * 64;

  f4 z = {0.f, 0.f, 0.f, 0.f};
  f4 accq[4][4];
#pragma unroll
  for (int i = 0; i < 4; ++i)
#pragma unroll
    for (int j = 0; j < 4; ++j) accq[i][j] = z;

  GEMM_PRE(wqb, xb)

  for (int t = 0; t < 8; ++t){
    STAGE(r0, t * 64)
    __syncthreads();               // DMA landed (all waves)
    GEMM_STEP(r0, accq)
    __syncthreads();               // WAR before next STAGE / qt overwrite
  }

  int head = blockIdx.y * 2 + (w >> 2);
  const unsigned short* kh = kb + (size_t)(b * NHEAD + head) * (KTOK * DH);
  const unsigned short* vh = vt + (size_t)(b * NHEAD + head) * (DH * KTOK);
  unsigned short* qt = &r0[w * 2048];          // per-wave 32x64 half-tile (4KB)
  unsigned short* op = att + ((size_t)(b * NPIX) + n0 + nl) * CDIM + head * 64;

#pragma unroll
  for (int nh = 0; nh < 2; ++nh){
    // q half (D-layout: row(dd)=fi*16+hi*4+r, col(n)=fj*16+lo) -> qt[n 0..31][dd], swizzled
#pragma unroll
    for (int fi = 0; fi < 4; ++fi)
#pragma unroll
      for (int fjh = 0; fjh < 2; ++fjh){
        f4 v = accq[fi][nh * 2 + fjh];
        us4 pk = { f2bf(v[0]), f2bf(v[1]), f2bf(v[2]), f2bf(v[3]) };
        int row = fjh * 16 + lo;               // n (local within half)
        int col = fi * 16 + hi * 4;            // dd
        int cs  = (((col >> 3) ^ (row & 7)) << 3) | (col & 7);
        *(us4*)&qt[row * 64 + cs] = pk;
      }

    // S^T[kk][n] = sum_dd k[kk][dd] * q[n][dd] ; kb pre-scaled by 1/sqrt(d)
    f4 accs[4][2];
#pragma unroll
    for (int i = 0; i < 4; ++i)
#pragma unroll
      for (int j = 0; j < 2; ++j) accs[i][j] = z;
    __builtin_amdgcn_s_setprio(1);
#pragma unroll
    for (int ks = 0; ks < 2; ++ks){
      bf8 ka[4];
#pragma unroll
      for (int fi = 0; fi < 4; ++fi)
        ka[fi] = *(const bf8*)(kh + (fi * 16 + lo) * 64 + ks * 32 + hi * 8);
#pragma unroll
      for (int fjh = 0; fjh < 2; ++fjh){
        bf8 qf = *(const bf8*)&qt[(fjh * 16 + lo) * 64 + (((ks * 4 + hi) ^ (lo & 7)) << 3)];
#pragma unroll
        for (int fi = 0; fi < 4; ++fi)
          accs[fi][fjh] = __builtin_amdgcn_mfma_f32_16x16x32_bf16(ka[fi], qf, accs[fi][fjh], 0, 0, 0);
      }
    }
    __builtin_amdgcn_s_setprio(0);

    // Softmax over kk per n-column; P overwrites qt (wave-local WAR)
#pragma unroll
    for (int fjh = 0; fjh < 2; ++fjh){
      float mx = accs[0][fjh][0];
#pragma unroll
      for (int fi = 0; fi < 4; ++fi)
#pragma unroll
        for (int r = 0; r < 4; ++r) mx = fmaxf(mx, accs[fi][fjh][r]);
      mx = fmaxf(mx, __shfl_xor(mx, 16));
      mx = fmaxf(mx, __shfl_xor(mx, 32));
      float sm = 0.f;
#pragma unroll
      for (int fi = 0; fi < 4; ++fi)
#pragma unroll
        for (int r = 0; r < 4; ++r){
          float e = __expf(accs[fi][fjh][r] - mx);
          accs[fi][fjh][r] = e; sm += e;
        }
      sm += __shfl_xor(sm, 16);
      sm += __shfl_xor(sm, 32);
      float inv = 1.0f / sm;
#pragma unroll
      for (int fi = 0; fi < 4; ++fi){
        us4 pk = { f2bf(accs[fi][fjh][0] * inv), f2bf(accs[fi][fjh][1] * inv),
                   f2bf(accs[fi][fjh][2] * inv), f2bf(accs[fi][fjh][3] * inv) };
        int row = fjh * 16 + lo;
        int col = fi * 16 + hi * 4;
        int cs  = (((col >> 3) ^ (row & 7)) << 3) | (col & 7);
        *(us4*)&qt[row * 64 + cs] = pk;
      }
    }

    // out^T[dd][n] = sum_kk vt[dd][kk] * P[n][kk]
    f4 acco[4][2];
#pragma unroll
    for (int i = 0; i < 4; ++i)
#pragma unroll
      for (int j = 0; j < 2; ++j) acco[i][j] = z;
    __builtin_amdgcn_s_setprio(1);
#pragma unroll
    for (int ks = 0; ks < 2; ++ks){
      int sw = (((ks * 4 + hi) ^ (lo & 7)) << 3);
      bf8 va[4];
#pragma unroll
      for (int fi = 0; fi < 4; ++fi)
        va[fi] = *(const bf8*)(vh + (fi * 16 + lo) * 64 + ks * 32 + hi * 8);
#pragma unroll
      for (int fjh = 0; fjh < 2; ++fjh){
        bf8 pf = *(const bf8*)&qt[(fjh * 16 + lo) * 64 + sw];
#pragma unroll
        for (int fi = 0; fi < 4; ++fi)
          acco[fi][fjh] = __builtin_amdgcn_mfma_f32_16x16x32_bf16(va[fi], pf, acco[fi][fjh], 0, 0, 0);
      }
    }
    __builtin_amdgcn_s_setprio(0);

    // att[b][n][c] bf16; c = head*64 + dd
#pragma unroll
    for (int fi = 0; fi < 4; ++fi)
#pragma unroll
      for (int fjh = 0; fjh < 2; ++fjh){
        f4 v = acco[fi][fjh];
        us4 pk = { f2bf(v[0]), f2bf(v[1]), f2bf(v[2]), f2bf(v[3]) };
        *(us4*)(op + (size_t)(nh * 32 + fjh * 16 + lo) * CDIM + fi * 16 + hi * 4) = pk;
      }
  }
}

// ---------------- K3: output projection + bias + residual (R14-verified verbatim) ----------------
__global__ __launch_bounds__(512, 4) void pproj(const unsigned short* __restrict__ wpb,
                                                const unsigned short* __restrict__ att,
                                                const float* __restrict__ x,
                                                const float* __restrict__ bpv,
                                                float* __restrict__ out){
  __shared__ __align__(16) unsigned short ab[24576];   // 48 KB: A + B
  int tid = threadIdx.x;
  int w = tid >> 6, l = tid & 63;
  int lo = l & 15, hi = l >> 4;
  int n0 = blockIdx.x * 256, o0 = blockIdx.y * 128, b = blockIdx.z;
  int ol = (w >> 2) * 64, nl = (w & 3) * 64;

  f4 z = {0.f, 0.f, 0.f, 0.f};
  f4 acc[4][4];
#pragma unroll
  for (int i = 0; i < 4; ++i)
#pragma unroll
    for (int j = 0; j < 4; ++j) acc[i][j] = z;

  GEMM_PRE(wpb, att)

  for (int t = 0; t < 8; ++t){
    STAGE(ab, t * 64)
    __syncthreads();
    GEMM_STEP(ab, acc)
    __syncthreads();
  }

#pragma unroll
  for (int fi = 0; fi < 4; ++fi)
#pragma unroll
    for (int fj = 0; fj < 4; ++fj){
      int o = o0 + ol + fi * 16 + hi * 4;
      int n = n0 + nl + fj * 16 + lo;
#pragma unroll
      for (int r = 0; r < 4; ++r){
        size_t idx = ((size_t)(b * CDIM + o + r)) * NPIX + n;
        out[idx] = acc[fi][fj][r] + bpv[o + r] + x[idx];
      }
    }
}

extern "C" void kernel_launch(void* const* d_in, const int* in_sizes, int n_in,
                              void* d_out, int out_size, void* d_ws, size_t ws_size,
                              hipStream_t stream){
  const float* x  = (const float*)d_in[0];
  const float* Ft = (const float*)d_in[1];
  const float* Wq = (const float*)d_in[2];
  const float* Wk = (const float*)d_in[3];
  const float* Wv = (const float*)d_in[4];
  const float* Wp = (const float*)d_in[5];
  const float* bp = (const float*)d_in[6];
  float* out = (float*)d_out;

  char* ws = (char*)d_ws;
  // ws layout (bytes): wqb 512K | wpb 512K | xb 32M | att 32M | kb 512K | vt 512K (~66MB)
  unsigned short* wqb = (unsigned short*)(ws);
  unsigned short* wpb = (unsigned short*)(ws + 524288);
  unsigned short* xb  = (unsigned short*)(ws + 1048576);
  unsigned short* att = (unsigned short*)(ws + 1048576 + 33554432);
  unsigned short* kb  = (unsigned short*)(ws + 1048576 + 2ull * 33554432);
  unsigned short* vt  = (unsigned short*)(ws + 1048576 + 2ull * 33554432 + 524288);

  wconv<<<dim3(256), dim3(256), 0, stream>>>(Wq, Wp, wqb, wpb);
  xtrans<<<dim3(64, 8, 8), dim3(256), 0, stream>>>(x, xb);
  kvproj<<<dim3(4, 8, 8), dim3(256), 0, stream>>>(Ft, Wk, Wv, kb, vt);
  qattn<<<dim3(16, 4, 8), dim3(512), 0, stream>>>(wqb, xb, kb, vt, att);
  pproj<<<dim3(16, 4, 8), dim3(512), 0, stream>>>(wpb, att, x, bp, out);
}

// Round 21
// 113.844 us; speedup vs baseline: 1.0486x; 1.0486x over previous
//
#include <hip/hip_runtime.h>
#include <cstdint>
#include <cstddef>

// Problem constants
#define BATCH 8
#define CDIM  512
#define NPIX  4096   // 64*64
#define NHEAD 8
#define DH    64
#define KTOK  64
#define MEM   512

typedef __attribute__((ext_vector_type(8))) short          bf8;   // MFMA A/B operand (8 bf16)
typedef __attribute__((ext_vector_type(4))) float          f4;    // MFMA C/D
typedef __attribute__((ext_vector_type(4))) unsigned short us4;   // 8-byte bf16 pack

__device__ __forceinline__ unsigned short f2bf(float f){
  union { float f; unsigned int u; } x; x.f = f;
  unsigned int r = (x.u + 0x7fffu + ((x.u >> 16) & 1u)) >> 16;
  return (unsigned short)r;
}

// async global->LDS DMA, 16B per lane; LDS dest = wave-uniform base + lane*16
__device__ __forceinline__ void gld_lds16(const unsigned short* g, unsigned short* lds){
  __builtin_amdgcn_global_load_lds((const __attribute__((address_space(1))) unsigned int*)g,
                                   (__attribute__((address_space(3))) unsigned int*)lds, 16, 0, 0);
}

// ---------------- K0: weights fp32 -> bf16 ----------------
__global__ __launch_bounds__(256) void wconv(const float* __restrict__ wq, const float* __restrict__ wp,
                                             unsigned short* __restrict__ wqb, unsigned short* __restrict__ wpb){
  int i = (blockIdx.x * 256 + threadIdx.x) * 4;   // grid 256 -> covers 262144
  float4 a = *(const float4*)(wq + i);
  us4 pa = { f2bf(a.x), f2bf(a.y), f2bf(a.z), f2bf(a.w) };
  *(us4*)(wqb + i) = pa;
  float4 b = *(const float4*)(wp + i);
  us4 pb = { f2bf(b.x), f2bf(b.y), f2bf(b.z), f2bf(b.w) };
  *(us4*)(wpb + i) = pb;
}

// ---------------- K0b: x [b][c][n] fp32 -> xb [b][n][c] bf16 ----------------
__global__ __launch_bounds__(256) void xtrans(const float* __restrict__ x, unsigned short* __restrict__ xb){
  __shared__ __align__(16) unsigned short t[64 * 68];
  int tid = threadIdx.x;
  int n0 = blockIdx.x * 64, c0 = blockIdx.y * 64, b = blockIdx.z;
  const float* xp = x + ((size_t)(b * CDIM + c0)) * NPIX + n0;
#pragma unroll
  for (int it = 0; it < 4; ++it){
    int idx = it * 1024 + tid * 4;
    int cc = idx >> 6, nn = idx & 63;
    float4 v = *(const float4*)(xp + (size_t)cc * NPIX + nn);
    us4 pk = { f2bf(v.x), f2bf(v.y), f2bf(v.z), f2bf(v.w) };
    *(us4*)&t[cc * 68 + nn] = pk;
  }
  __syncthreads();
  unsigned short* op = xb + ((size_t)(b * NPIX + n0)) * CDIM + c0;
#pragma unroll
  for (int it = 0; it < 4; ++it){
    int idx = it * 1024 + tid * 4;
    int nn = idx >> 6, c4 = idx & 63;
    us4 pk = { t[(c4 + 0) * 68 + nn], t[(c4 + 1) * 68 + nn],
               t[(c4 + 2) * 68 + nn], t[(c4 + 3) * 68 + nn] };
    *(us4*)(op + (size_t)nn * CDIM + c4) = pk;
  }
}

// ---------------- K1: K/V projection (fp32 compute, bf16 out) ----------------
__global__ __launch_bounds__(256) void kvproj(const float* __restrict__ Ft, const float* __restrict__ Wk,
                                              const float* __restrict__ Wv, unsigned short* __restrict__ kb,
                                              unsigned short* __restrict__ vt){
  __shared__ float ft[8][MEM];
  int tid = threadIdx.x;
  int cg = blockIdx.x, kk0 = blockIdx.y * 8, b = blockIdx.z;
  const float* fp = Ft + ((size_t)(b * KTOK + kk0)) * MEM;
#pragma unroll
  for (int it = 0; it < 4; ++it){
    int idx = it * 1024 + tid * 4;
    int row = idx >> 9, m = idx & 511;
    *(float4*)&ft[row][m] = *(const float4*)(fp + (size_t)row * MEM + m);
  }
  __syncthreads();
  int kv = tid >> 7, cl = tid & 127;
  int c = cg * 128 + cl;
  const float* wrow = (kv ? Wv : Wk) + (size_t)c * MEM;
  float acc[8] = {0.f,0.f,0.f,0.f,0.f,0.f,0.f,0.f};
  for (int m = 0; m < MEM; m += 4){
    float4 wv4 = *(const float4*)(wrow + m);
#pragma unroll
    for (int kk = 0; kk < 8; ++kk){
      acc[kk] += wv4.x * ft[kk][m] + wv4.y * ft[kk][m+1] + wv4.z * ft[kk][m+2] + wv4.w * ft[kk][m+3];
    }
  }
  int h = c >> 6, dd = c & 63;
  if (kv == 0){
#pragma unroll
    for (int kk = 0; kk < 8; ++kk)
      kb[(((size_t)(b * NHEAD + h)) * KTOK + kk0 + kk) * DH + dd] = f2bf(acc[kk] * 0.125f);
  } else {
#pragma unroll
    for (int kk = 0; kk < 8; ++kk)
      vt[(((size_t)(b * NHEAD + h)) * DH + dd) * KTOK + kk0 + kk] = f2bf(acc[kk]);
  }
}

// ====== GEMM geometry (R14-verified): 128o x 256n tile, 8 waves (2 o x 4 n), BK=64, ======
// ====== single-buffer {STAGE; sync; MFMA; sync}, conflict-free swizzle ======
// LDS: A [0,8192) rows 0..127 | B [8192,24576) rows 0..255 shorts; rows 128B, 16B chunks,
// phys chunk = logical ^ (row&7). STAGE: 48 DMAs/block = 6/wave (A groups {w,w+8},
// B groups {w,w+8,w+16,w+24}); lane l -> row l>>3 of its group, src pre-swizzled (l&7)^(l>>3).
#define GEMM_PRE(APTR, BPTR)                                                              \
  const int lrow = l >> 3;                                                                \
  const int lchk = (l & 7) ^ lrow;                                                        \
  const unsigned short* aS = (APTR) + (size_t)(o0 + w * 8 + lrow) * CDIM + lchk * 8;      \
  const unsigned short* bS = (BPTR) + ((size_t)(b * NPIX) + n0 + w * 8 + lrow) * CDIM + lchk * 8;

#define STAGE(LDS, kc)                                                                    \
  {                                                                                       \
    gld_lds16(aS + (kc),                        &(LDS)[w * 512]);                         \
    gld_lds16(aS + (size_t)64 * CDIM + (kc),    &(LDS)[(w + 8) * 512]);                   \
    _Pragma("unroll")                                                                     \
    for (int j = 0; j < 4; ++j)                                                           \
      gld_lds16(bS + (size_t)j * 64 * CDIM + (kc), &(LDS)[8192 + (w + j * 8) * 512]);     \
  }

#define GEMM_STEP(LDS, ACC)                                                               \
  _Pragma("unroll")                                                                       \
  for (int ks = 0; ks < 2; ++ks){                                                         \
    bf8 af[4], bfr[4];                                                                    \
    _Pragma("unroll")                                                                     \
    for (int fi = 0; fi < 4; ++fi){                                                       \
      int r = ol + fi * 16 + lo;                                                          \
      af[fi] = *(const bf8*)&(LDS)[r * 64 + (((ks * 4 + hi) ^ (r & 7)) << 3)];            \
    }                                                                                     \
    _Pragma("unroll")                                                                     \
    for (int fj = 0; fj < 4; ++fj){                                                       \
      int r = nl + fj * 16 + lo;                                                          \
      bfr[fj] = *(const bf8*)&(LDS)[8192 + r * 64 + (((ks * 4 + hi) ^ (r & 7)) << 3)];    \
    }                                                                                     \
    _Pragma("unroll")                                                                     \
    for (int fi = 0; fi < 4; ++fi)                                                        \
      _Pragma("unroll")                                                                   \
      for (int fj = 0; fj < 4; ++fj)                                                      \
        ACC[fi][fj] = __builtin_amdgcn_mfma_f32_16x16x32_bf16(af[fi], bfr[fj], ACC[fi][fj], 0, 0, 0); \
  }

// ---------------- K2: fused q-projection + attention (R14 structure + T5 setprio on tail) ----------------
// grid (16,4,8): x = 256-n tile, y = 128-o tile (head pair), z = batch. Wave w: head
// blockIdx.y*2+(w>>2), n-quarter (w&3). qt/P per-wave 64x64 swizzled tile aliases staging.
__global__ __launch_bounds__(512, 4) void qattn(const unsigned short* __restrict__ wqb,
                                                const unsigned short* __restrict__ xb,
                                                const unsigned short* __restrict__ kb,
                                                const unsigned short* __restrict__ vt,
                                                unsigned short* __restrict__ att){
  __shared__ __align__(16) unsigned short r0[32768];   // 64 KB: staging 48 KB; qt 8x8KB aliases
  int tid = threadIdx.x;
  int w = tid >> 6, l = tid & 63;
  int lo = l & 15, hi = l >> 4;
  int n0 = blockIdx.x * 256, o0 = blockIdx.y * 128, b = blockIdx.z;
  int ol = (w >> 2) * 64, nl = (w & 3) * 64;

  f4 z = {0.f, 0.f, 0.f, 0.f};
  f4 accq[4][4];
#pragma unroll
  for (int i = 0; i < 4; ++i)
#pragma unroll
    for (int j = 0; j < 4; ++j) accq[i][j] = z;

  GEMM_PRE(wqb, xb)

  for (int t = 0; t < 8; ++t){
    STAGE(r0, t * 64)
    __syncthreads();               // DMA landed (all waves)
    GEMM_STEP(r0, accq)
    __syncthreads();               // WAR before next STAGE / qt overwrite
  }

  // q (D-layout: row(dd)=fi*16+hi*4+r, col(n)=fj*16+lo) -> qt[n][dd] bf16, swizzled
  unsigned short* qt = &r0[w * 4096];
#pragma unroll
  for (int fi = 0; fi < 4; ++fi)
#pragma unroll
    for (int fj = 0; fj < 4; ++fj){
      f4 v = accq[fi][fj];
      us4 pk = { f2bf(v[0]), f2bf(v[1]), f2bf(v[2]), f2bf(v[3]) };
      int row = fj * 16 + lo;                  // n (local)
      int col = fi * 16 + hi * 4;              // dd
      int cs  = (((col >> 3) ^ (row & 7)) << 3) | (col & 7);
      *(us4*)&qt[row * 64 + cs] = pk;
    }

  int head = blockIdx.y * 2 + (w >> 2);
  // S^T[kk][n] = sum_dd k[kk][dd] * q[n][dd] ; kb pre-scaled by 1/sqrt(d)
  const unsigned short* kh = kb + (size_t)(b * NHEAD + head) * (KTOK * DH);
  f4 accs[4][4];
#pragma unroll
  for (int i = 0; i < 4; ++i)
#pragma unroll
    for (int j = 0; j < 4; ++j) accs[i][j] = z;
  __builtin_amdgcn_s_setprio(1);   // T5: per-wave independent MFMA phase (m191 +4-7% case)
#pragma unroll
  for (int ks = 0; ks < 2; ++ks){
    bf8 ka[4];
#pragma unroll
    for (int fi = 0; fi < 4; ++fi)
      ka[fi] = *(const bf8*)(kh + (fi * 16 + lo) * 64 + ks * 32 + hi * 8);
#pragma unroll
    for (int fj = 0; fj < 4; ++fj){
      bf8 qf = *(const bf8*)&qt[(fj * 16 + lo) * 64 + (((ks * 4 + hi) ^ (lo & 7)) << 3)];
#pragma unroll
      for (int fi = 0; fi < 4; ++fi)
        accs[fi][fj] = __builtin_amdgcn_mfma_f32_16x16x32_bf16(ka[fi], qf, accs[fi][fj], 0, 0, 0);
    }
  }
  __builtin_amdgcn_s_setprio(0);

  // Softmax over kk per n-column: 16 local (fi x r) + shuffles l^16, l^32; P overwrites qt
#pragma unroll
  for (int fj = 0; fj < 4; ++fj){
    float mx = accs[0][fj][0];
#pragma unroll
    for (int fi = 0; fi < 4; ++fi)
#pragma unroll
      for (int r = 0; r < 4; ++r) mx = fmaxf(mx, accs[fi][fj][r]);
    mx = fmaxf(mx, __shfl_xor(mx, 16));
    mx = fmaxf(mx, __shfl_xor(mx, 32));
    float sm = 0.f;
#pragma unroll
    for (int fi = 0; fi < 4; ++fi)
#pragma unroll
      for (int r = 0; r < 4; ++r){
        float e = __expf(accs[fi][fj][r] - mx);
        accs[fi][fj][r] = e; sm += e;
      }
    sm += __shfl_xor(sm, 16);
    sm += __shfl_xor(sm, 32);
    float inv = 1.0f / sm;
#pragma unroll
    for (int fi = 0; fi < 4; ++fi){
      us4 pk = { f2bf(accs[fi][fj][0] * inv), f2bf(accs[fi][fj][1] * inv),
                 f2bf(accs[fi][fj][2] * inv), f2bf(accs[fi][fj][3] * inv) };
      int row = fj * 16 + lo;
      int col = fi * 16 + hi * 4;
      int cs  = (((col >> 3) ^ (row & 7)) << 3) | (col & 7);
      *(us4*)&qt[row * 64 + cs] = pk;
    }
  }

  // out^T[dd][n] = sum_kk vt[dd][kk] * P[n][kk]
  const unsigned short* vh = vt + (size_t)(b * NHEAD + head) * (DH * KTOK);
  f4 acco[4][4];
#pragma unroll
  for (int i = 0; i < 4; ++i)
#pragma unroll
    for (int j = 0; j < 4; ++j) acco[i][j] = z;
  __builtin_amdgcn_s_setprio(1);
#pragma unroll
  for (int ks = 0; ks < 2; ++ks){
    int sw = (((ks * 4 + hi) ^ (lo & 7)) << 3);
    bf8 va[4];
#pragma unroll
    for (int fi = 0; fi < 4; ++fi)
      va[fi] = *(const bf8*)(vh + (fi * 16 + lo) * 64 + ks * 32 + hi * 8);
#pragma unroll
    for (int fj = 0; fj < 4; ++fj){
      bf8 pf = *(const bf8*)&qt[(fj * 16 + lo) * 64 + sw];
#pragma unroll
      for (int fi = 0; fi < 4; ++fi)
        acco[fi][fj] = __builtin_amdgcn_mfma_f32_16x16x32_bf16(va[fi], pf, acco[fi][fj], 0, 0, 0);
    }
  }
  __builtin_amdgcn_s_setprio(0);

  // att[b][n][c] bf16; c = head*64 + dd
  unsigned short* op = att + ((size_t)(b * NPIX) + n0 + nl) * CDIM + head * 64;
#pragma unroll
  for (int fi = 0; fi < 4; ++fi)
#pragma unroll
    for (int fj = 0; fj < 4; ++fj){
      f4 v = acco[fi][fj];
      us4 pk = { f2bf(v[0]), f2bf(v[1]), f2bf(v[2]), f2bf(v[3]) };
      *(us4*)(op + (size_t)(fj * 16 + lo) * CDIM + fi * 16 + hi * 4) = pk;
    }
}

// ---------------- K3: output projection + bias + residual (R14-verified verbatim) ----------------
__global__ __launch_bounds__(512, 4) void pproj(const unsigned short* __restrict__ wpb,
                                                const unsigned short* __restrict__ att,
                                                const float* __restrict__ x,
                                                const float* __restrict__ bpv,
                                                float* __restrict__ out){
  __shared__ __align__(16) unsigned short ab[24576];   // 48 KB: A + B
  int tid = threadIdx.x;
  int w = tid >> 6, l = tid & 63;
  int lo = l & 15, hi = l >> 4;
  int n0 = blockIdx.x * 256, o0 = blockIdx.y * 128, b = blockIdx.z;
  int ol = (w >> 2) * 64, nl = (w & 3) * 64;

  f4 z = {0.f, 0.f, 0.f, 0.f};
  f4 acc[4][4];
#pragma unroll
  for (int i = 0; i < 4; ++i)
#pragma unroll
    for (int j = 0; j < 4; ++j) acc[i][j] = z;

  GEMM_PRE(wpb, att)

  for (int t = 0; t < 8; ++t){
    STAGE(ab, t * 64)
    __syncthreads();
    GEMM_STEP(ab, acc)
    __syncthreads();
  }

#pragma unroll
  for (int fi = 0; fi < 4; ++fi)
#pragma unroll
    for (int fj = 0; fj < 4; ++fj){
      int o = o0 + ol + fi * 16 + hi * 4;
      int n = n0 + nl + fj * 16 + lo;
#pragma unroll
      for (int r = 0; r < 4; ++r){
        size_t idx = ((size_t)(b * CDIM + o + r)) * NPIX + n;
        out[idx] = acc[fi][fj][r] + bpv[o + r] + x[idx];
      }
    }
}

extern "C" void kernel_launch(void* const* d_in, const int* in_sizes, int n_in,
                              void* d_out, int out_size, void* d_ws, size_t ws_size,
                              hipStream_t stream){
  const float* x  = (const float*)d_in[0];
  const float* Ft = (const float*)d_in[1];
  const float* Wq = (const float*)d_in[2];
  const float* Wk = (const float*)d_in[3];
  const float* Wv = (const float*)d_in[4];
  const float* Wp = (const float*)d_in[5];
  const float* bp = (const float*)d_in[6];
  float* out = (float*)d_out;

  char* ws = (char*)d_ws;
  // ws layout (bytes): wqb 512K | wpb 512K | xb 32M | att 32M | kb 512K | vt 512K (~66MB)
  unsigned short* wqb = (unsigned short*)(ws);
  unsigned short* wpb = (unsigned short*)(ws + 524288);
  unsigned short* xb  = (unsigned short*)(ws + 1048576);
  unsigned short* att = (unsigned short*)(ws + 1048576 + 33554432);
  unsigned short* kb  = (unsigned short*)(ws + 1048576 + 2ull * 33554432);
  unsigned short* vt  = (unsigned short*)(ws + 1048576 + 2ull * 33554432 + 524288);

  wconv<<<dim3(256), dim3(256), 0, stream>>>(Wq, Wp, wqb, wpb);
  xtrans<<<dim3(64, 8, 8), dim3(256), 0, stream>>>(x, xb);
  kvproj<<<dim3(4, 8, 8), dim3(256), 0, stream>>>(Ft, Wk, Wv, kb, vt);
  qattn<<<dim3(16, 4, 8), dim3(512), 0, stream>>>(wqb, xb, kb, vt, att);
  pproj<<<dim3(16, 4, 8), dim3(512), 0, stream>>>(wpb, att, x, bp, out);
}